// Round 1
// baseline (1013.285 us; speedup 1.0000x reference)
//
#include <hip/hip_runtime.h>
#include <math.h>

// Problem constants (match reference)
#define Bb   4
#define NBb  2048
#define Lb   16
#define Cb   128
#define Hb   8
#define Db   16
#define EGH  16
#define NTHREADS 384

__global__ __launch_bounds__(NTHREADS) void leaf_attn_kernel(
    const float* __restrict__ x,
    const int*   __restrict__ attn_mask,
    const float* __restrict__ edge,
    const float* __restrict__ Wqkv, const float* __restrict__ bqkv,
    const float* __restrict__ Wproj, const float* __restrict__ bproj,
    const float* __restrict__ eg_w1, const float* __restrict__ eg_b1,
    const float* __restrict__ eg_w2, const float* __restrict__ eg_b2,
    const float* __restrict__ Wbr,  const float* __restrict__ bbr,
    float* __restrict__ out)
{
    constexpr int XP = Cb + 4;     // padded stride for x-like tiles (bank spread)
    constexpr int QP = 3*Cb + 1;   // padded stride for qkv tile

    __shared__ float xS[Lb * XP];        // 16 x 132
    __shared__ float qkvS[Lb * QP];      // 16 x 385
    __shared__ float mS[Lb * Lb];
    __shared__ float logitS[Lb * Lb];
    __shared__ float ewS[Lb * Lb * (Hb + 1)];  // [q][k][h] padded
    __shared__ float xmidS[Lb * XP];
    __shared__ float blkS[Cb];
    __shared__ float vblkS[Cb];

    const int bid = blockIdx.x;          // b*NB + nb
    const int tid = threadIdx.x;
    const float* xb = x + (size_t)bid * (Lb * Cb);

    // ---- phase 0: load x block + raw mask ----
    for (int i = tid; i < Lb * Cb / 4; i += NTHREADS) {
        int t  = i >> 5;     // 32 float4 per row
        int c4 = i & 31;
        float4 v = ((const float4*)xb)[i];
        *(float4*)&xS[t * XP + c4 * 4] = v;
    }
    if (tid < Lb * Lb) {
        mS[tid] = (float)attn_mask[(size_t)bid * Lb * Lb + tid];
    }
    __syncthreads();

    // ---- phase 1: diag fix (need), block mean ----
    if (tid < Lb) {
        float s = 0.f;
        #pragma unroll
        for (int k = 0; k < Lb; ++k) s += mS[tid * Lb + k];
        if (s < 1.f) mS[tid * Lb + tid] = 1.f;   // max(diag, need) with 0/1 values
    } else if (tid >= 64 && tid < 64 + Cb) {
        int c = tid - 64;
        float s = 0.f;
        #pragma unroll
        for (int t = 0; t < Lb; ++t) s += xS[t * XP + c];
        blkS[c] = s * (1.f / 16.f);
    }
    __syncthreads();

    // ---- phase 2a: qkv (thread = Wqkv row), also v_blk for rows >= 2C ----
    {
        const int r = tid;   // 0..383
        const float* wrow = Wqkv + r * Cb;
        float acc[Lb];
        #pragma unroll
        for (int t = 0; t < Lb; ++t) acc[t] = 0.f;
        float accB = 0.f;
        const bool isV = (r >= 2 * Cb);   // wave-uniform (waves 4,5)
        for (int c = 0; c < Cb; c += 4) {
            float4 w4 = *(const float4*)&wrow[c];
            #pragma unroll
            for (int t = 0; t < Lb; ++t) {
                float4 x4 = *(const float4*)&xS[t * XP + c];
                acc[t] += w4.x * x4.x + w4.y * x4.y + w4.z * x4.z + w4.w * x4.w;
            }
            if (isV) {
                float4 b4 = *(const float4*)&blkS[c];
                accB += w4.x * b4.x + w4.y * b4.y + w4.z * b4.z + w4.w * b4.w;
            }
        }
        float bias = bqkv[r];
        #pragma unroll
        for (int t = 0; t < Lb; ++t) qkvS[t * QP + r] = acc[t] + bias;
        if (isV) vblkS[r - 2 * Cb] = accB + bias;
    }

    // ---- phase 2b: edge-gate MLP + logits (threads < 256; mS is final) ----
    if (tid < Lb * Lb) {
        const int q = tid >> 4, k = tid & 15;
        float bp0, bp1, bp2, bp3;
        if (q == k) { bp0 = bp1 = bp2 = 0.f; bp3 = 1.f; }
        else {
            const float* e = edge + ((size_t)bid * Lb * Lb + tid) * 4;
            bp0 = e[0]; bp1 = e[1]; bp2 = e[2]; bp3 = e[3];
        }
        const float mv = mS[tid];
        logitS[tid] = (mv == 0.f) ? -INFINITY : bp3;

        float ew[Hb];
        #pragma unroll
        for (int h = 0; h < Hb; ++h) ew[h] = eg_b2[h];
        #pragma unroll
        for (int j = 0; j < EGH; ++j) {
            float z = eg_w1[j*4+0]*bp0 + eg_w1[j*4+1]*bp1 +
                      eg_w1[j*4+2]*bp2 + eg_w1[j*4+3]*bp3 + eg_b1[j];
            float g = 0.5f * z * (1.f + erff(z * 0.70710678118654752f));
            #pragma unroll
            for (int h = 0; h < Hb; ++h) ew[h] += eg_w2[h*EGH + j] * g;
        }
        #pragma unroll
        for (int h = 0; h < Hb; ++h)
            ewS[tid * (Hb + 1) + h] = (mv == 0.f) ? 0.f : ew[h];
    }
    __syncthreads();

    // ---- phase 3: attention + ew mixing + block-node gate (threads < 128) ----
    if (tid < Hb * Lb) {
        const int h = tid & 7;
        const int q = tid >> 3;

        float sc[Lb];
        const float* qv = &qkvS[q * QP + h * Db];
        float mx = -INFINITY;
        #pragma unroll
        for (int k = 0; k < Lb; ++k) {
            const float* kv = &qkvS[k * QP + Cb + h * Db];
            float s = 0.f;
            #pragma unroll
            for (int d = 0; d < Db; ++d) s += qv[d] * kv[d];
            s = s * 0.25f + logitS[q * Lb + k];
            sc[k] = s;
            mx = fmaxf(mx, s);
        }
        float sum = 0.f;
        #pragma unroll
        for (int k = 0; k < Lb; ++k) { sc[k] = expf(sc[k] - mx); sum += sc[k]; }
        const float inv = 1.f / sum;
        #pragma unroll
        for (int k = 0; k < Lb; ++k)
            sc[k] = sc[k] * inv + ewS[(q * Lb + k) * (Hb + 1) + h];

        // block-node gate
        float gz = bbr[h];
        const float* wb = Wbr + h * Cb;
        for (int c = 0; c < Cb; c += 4) {
            float4 w4 = *(const float4*)&wb[c];
            float4 x4 = *(const float4*)&xS[q * XP + c];
            gz += w4.x * x4.x + w4.y * x4.y + w4.z * x4.z + w4.w * x4.w;
        }
        const float g = 1.f / (1.f + expf(-gz));

        float acc[Db];
        #pragma unroll
        for (int d = 0; d < Db; ++d) acc[d] = g * vblkS[h * Db + d];
        #pragma unroll
        for (int k = 0; k < Lb; ++k) {
            const float coeff = sc[k];
            const float* vv = &qkvS[k * QP + 2 * Cb + h * Db];
            #pragma unroll
            for (int d = 0; d < Db; ++d) acc[d] += coeff * vv[d];
        }
        #pragma unroll
        for (int d = 0; d < Db; ++d) xmidS[q * XP + h * Db + d] = acc[d];
    }
    __syncthreads();

    // ---- phase 4: output projection ----
    for (int idx = tid; idx < Lb * Cb; idx += NTHREADS) {
        const int t = idx >> 7;
        const int j = idx & 127;
        const float* wrow = Wproj + j * Cb;
        float s = bproj[j];
        for (int c = 0; c < Cb; c += 4) {
            float4 w4 = *(const float4*)&wrow[c];
            float4 m4 = *(const float4*)&xmidS[t * XP + c];
            s += w4.x * m4.x + w4.y * m4.y + w4.z * m4.z + w4.w * m4.w;
        }
        out[(size_t)bid * (Lb * Cb) + idx] = s;
    }
}

extern "C" void kernel_launch(void* const* d_in, const int* in_sizes, int n_in,
                              void* d_out, int out_size, void* d_ws, size_t ws_size,
                              hipStream_t stream) {
    const float* x         = (const float*)d_in[0];
    const int*   attn_mask = (const int*)  d_in[1];
    const float* edge      = (const float*)d_in[2];
    const float* Wqkv      = (const float*)d_in[3];
    const float* bqkv      = (const float*)d_in[4];
    const float* Wproj     = (const float*)d_in[5];
    const float* bproj     = (const float*)d_in[6];
    const float* eg_w1     = (const float*)d_in[7];
    const float* eg_b1     = (const float*)d_in[8];
    const float* eg_w2     = (const float*)d_in[9];
    const float* eg_b2     = (const float*)d_in[10];
    const float* Wbr       = (const float*)d_in[11];
    const float* bbr       = (const float*)d_in[12];
    float* outp = (float*)d_out;

    dim3 grid(Bb * NBb);   // 8192 blocks, one per (b, nb)
    dim3 block(NTHREADS);
    hipLaunchKernelGGL(leaf_attn_kernel, grid, block, 0, stream,
                       x, attn_mask, edge, Wqkv, bqkv, Wproj, bproj,
                       eg_w1, eg_b1, eg_w2, eg_b2, Wbr, bbr, outp);
}

// Round 2
// 184.712 us; speedup vs baseline: 5.4858x; 5.4858x over previous
//
#include <hip/hip_runtime.h>
#include <hip/hip_bf16.h>
#include <math.h>

// B=4, NB=2048 -> 8192 leaf blocks of L=16 tokens x C=128; H=8 heads x D=16.
typedef __attribute__((ext_vector_type(8))) short bf16x8;
typedef __attribute__((ext_vector_type(4))) float f32x4;
typedef __attribute__((ext_vector_type(4))) unsigned short us4;

__device__ __forceinline__ unsigned short f2bf(float f) {
    union { __hip_bfloat16 h; unsigned short u; } cv;
    cv.h = __float2bfloat16(f);
    return cv.u;
}
__device__ __forceinline__ float bf2f(unsigned short u) {
    union { unsigned int i; float f; } cv;
    cv.i = ((unsigned int)u) << 16;
    return cv.f;
}
__device__ __forceinline__ f32x4 MFMA(bf16x8 a, bf16x8 b, f32x4 c) {
    return __builtin_amdgcn_mfma_f32_16x16x32_bf16(a, b, c, 0, 0, 0);
}

// ---- prep: Wbig = bf16([Wqkv(384); Wbr(8); zeros(8)]) [400][128]; Wp = bf16(Wproj) [128][128]
__global__ __launch_bounds__(256) void prep_kernel(
    const float* __restrict__ Wqkv, const float* __restrict__ Wbr,
    const float* __restrict__ Wproj,
    unsigned short* __restrict__ Wbig, unsigned short* __restrict__ Wp)
{
    int i = blockIdx.x * 256 + threadIdx.x;
    if (i < 400 * 128) {
        int n = i >> 7, k = i & 127;
        float v = (n < 384) ? Wqkv[i] : (n < 392 ? Wbr[(n - 384) * 128 + k] : 0.f);
        Wbig[i] = f2bf(v);
    } else {
        int j = i - 400 * 128;
        if (j < 128 * 128) Wp[j] = f2bf(Wproj[j]);
    }
}

__global__ __launch_bounds__(256) void leaf_main(
    const float* __restrict__ x, const int* __restrict__ mask,
    const float* __restrict__ edge,
    const unsigned short* __restrict__ Wbig, const unsigned short* __restrict__ Wp,
    const float* __restrict__ bqkv, const float* __restrict__ bproj,
    const float* __restrict__ eg_w1, const float* __restrict__ eg_b1,
    const float* __restrict__ eg_w2, const float* __restrict__ eg_b2,
    const float* __restrict__ bbr, float* __restrict__ out)
{
    // x staged bf16 hi/lo, chunk-XOR swizzled (16B chunks): conflict-free A-frag reads
    __shared__ unsigned short xhiS[16 * 128], xloS[16 * 128];
    __shared__ unsigned short qhiS[16 * 136], qloS[16 * 136];   // [tok][128+8]
    __shared__ unsigned short khiS[16 * 136], kloS[16 * 136];
    __shared__ unsigned short vtS[128 * 24];                    // [h*16+d][tok(24 pad)]
    __shared__ unsigned short ewS[256 * 8];                     // [q*16+k][h] bf16
    __shared__ float logitS[256];
    __shared__ float gS[16 * 8];                                // [tok][h]
    __shared__ float vbS[128];                                  // v_blk [h*16+d]
    __shared__ unsigned short pS[128 * 24];                     // [h*16+q][ktok(24)]
    __shared__ unsigned short mhiS[16 * 136], mloS[16 * 136];   // x_mid hi/lo

    const int bid  = blockIdx.x;
    const int tid  = threadIdx.x;
    const int lane = tid & 63;
    const int wave = tid >> 6;
    const int c15  = lane & 15;
    const int quad = lane >> 4;
    const bf16x8 zf = {0, 0, 0, 0, 0, 0, 0, 0};

    // ---- phase 0: stage x (f32 -> bf16 hi/lo, swizzled) ----
    {
        const float4* xb = (const float4*)(x + (size_t)bid * 2048);
        #pragma unroll
        for (int ii = 0; ii < 2; ++ii) {
            int i = tid + ii * 256;
            float4 v = xb[i];
            int row = i >> 5, c4 = i & 31;
            int off = row * 128 + (((c4 >> 1) ^ (row & 7)) << 3) + ((c4 & 1) << 2);
            float f[4] = {v.x, v.y, v.z, v.w};
            us4 hi, lo;
            #pragma unroll
            for (int j = 0; j < 4; ++j) {
                unsigned short h = f2bf(f[j]);
                hi[j] = h;
                lo[j] = f2bf(f[j] - bf2f(h));
            }
            *(us4*)&xhiS[off] = hi;
            *(us4*)&xloS[off] = lo;
        }
    }
    __syncthreads();

    // ---- phase 1: qkv + gate GEMM via MFMA (split-A: hi+lo) ----
    {
        bf16x8 ah[4], al[4];
        #pragma unroll
        for (int kk = 0; kk < 4; ++kk) {
            int off = c15 * 128 + (((kk * 4 + quad) ^ (c15 & 7)) << 3);
            ah[kk] = *(const bf16x8*)&xhiS[off];
            al[kk] = *(const bf16x8*)&xloS[off];
        }
        const int ntiles = (wave == 0) ? 7 : 6;   // wave0 also owns gate tile 24
        int nt = wave;
        bf16x8 bcur[4];
        {
            const unsigned short* wb = Wbig + (nt * 16 + c15) * 128 + quad * 8;
            #pragma unroll
            for (int kk = 0; kk < 4; ++kk) bcur[kk] = *(const bf16x8*)(wb + kk * 32);
        }
        for (int it = 0; it < ntiles; ++it) {
            int ntn = (it == 5) ? 24 : wave + (it + 1) * 4;
            bf16x8 bnxt[4] = {zf, zf, zf, zf};
            if (it + 1 < ntiles) {
                const unsigned short* wb = Wbig + (ntn * 16 + c15) * 128 + quad * 8;
                #pragma unroll
                for (int kk = 0; kk < 4; ++kk) bnxt[kk] = *(const bf16x8*)(wb + kk * 32);
            }
            f32x4 acc = {0.f, 0.f, 0.f, 0.f};
            #pragma unroll
            for (int kk = 0; kk < 4; ++kk) {
                acc = MFMA(ah[kk], bcur[kk], acc);
                acc = MFMA(al[kk], bcur[kk], acc);
            }
            if (nt < 24) {
                float bias = bqkv[nt * 16 + c15];
                #pragma unroll
                for (int r = 0; r < 4; ++r) {
                    int tok = quad * 4 + r;
                    float val = acc[r] + bias;
                    if (nt < 8) {
                        int col = nt * 16 + c15;
                        unsigned short h = f2bf(val);
                        qhiS[tok * 136 + col] = h;
                        qloS[tok * 136 + col] = f2bf(val - bf2f(h));
                    } else if (nt < 16) {
                        int col = (nt - 8) * 16 + c15;
                        unsigned short h = f2bf(val);
                        khiS[tok * 136 + col] = h;
                        kloS[tok * 136 + col] = f2bf(val - bf2f(h));
                    } else {
                        int c = (nt - 16) * 16 + c15;   // h*16+d
                        vtS[c * 24 + tok] = f2bf(val);
                    }
                }
            } else if (c15 < 8) {
                float bias = bbr[c15];
                #pragma unroll
                for (int r = 0; r < 4; ++r) {
                    int tok = quad * 4 + r;
                    gS[tok * 8 + c15] = 1.f / (1.f + __expf(-(acc[r] + bias)));
                }
            }
            #pragma unroll
            for (int kk = 0; kk < 4; ++kk) bcur[kk] = bnxt[kk];
            nt = ntn;
        }
    }

    // ---- phase 2: edge-gate MLP + mask/logits (all 256 threads, 1 pair each) ----
    {
        const int q = tid >> 4, k = tid & 15;
        int mv = mask[(size_t)bid * 256 + tid];
        int s = mv;
        s += __shfl_xor(s, 1); s += __shfl_xor(s, 2);
        s += __shfl_xor(s, 4); s += __shfl_xor(s, 8);
        float m = (float)mv;
        if (q == k && s < 1) m = 1.f;
        float bp0, bp1, bp2, bp3;
        if (q == k) { bp0 = bp1 = bp2 = 0.f; bp3 = 1.f; }
        else {
            const float4 e = *(const float4*)&edge[((size_t)bid * 256 + tid) * 4];
            bp0 = e.x; bp1 = e.y; bp2 = e.z; bp3 = e.w;
        }
        logitS[tid] = (m == 0.f) ? -INFINITY : bp3;
        float ew[8];
        #pragma unroll
        for (int h = 0; h < 8; ++h) ew[h] = eg_b2[h];
        #pragma unroll
        for (int j = 0; j < 16; ++j) {
            float z = eg_w1[j * 4 + 0] * bp0 + eg_w1[j * 4 + 1] * bp1 +
                      eg_w1[j * 4 + 2] * bp2 + eg_w1[j * 4 + 3] * bp3 + eg_b1[j];
            float g = 0.5f * z * (1.f + erff(z * 0.70710678118654752f));
            #pragma unroll
            for (int h = 0; h < 8; ++h) ew[h] += eg_w2[h * 16 + j] * g;
        }
        #pragma unroll
        for (int h = 0; h < 8; ++h)
            ewS[tid * 8 + h] = f2bf((m == 0.f) ? 0.f : ew[h]);
    }
    __syncthreads();

    // ---- phase 3: attention (2 heads per wave) ----
    {
        if (lane < 32) {   // v_blk for this wave's two heads
            int h = 2 * wave + quad, d = c15;
            float sum = 0.f;
            #pragma unroll
            for (int t = 0; t < 16; ++t) sum += bf2f(vtS[(h * 16 + d) * 24 + t]);
            vbS[h * 16 + d] = sum * 0.0625f;
        }
        #pragma unroll
        for (int hh = 0; hh < 2; ++hh) {
            const int h = 2 * wave + hh;
            const int fo = c15 * 136 + h * 16 + (quad & 1) * 8;
            bf16x8 qh_ = *(const bf16x8*)&qhiS[fo];
            bf16x8 ql_ = *(const bf16x8*)&qloS[fo];
            bf16x8 kh_ = *(const bf16x8*)&khiS[fo];
            bf16x8 kl_ = *(const bf16x8*)&kloS[fo];
            if (quad >= 2) { qh_ = zf; ql_ = zf; kh_ = zf; kl_ = zf; }
            f32x4 sc = {0.f, 0.f, 0.f, 0.f};
            sc = MFMA(qh_, kh_, sc);   // scores with 2-term split (drop lo*lo)
            sc = MFMA(qh_, kl_, sc);
            sc = MFMA(ql_, kh_, sc);
            #pragma unroll
            for (int r = 0; r < 4; ++r) {
                const int q = quad * 4 + r;
                float s = sc[r] * 0.25f + logitS[q * 16 + c15];
                float mx = s;
                mx = fmaxf(mx, __shfl_xor(mx, 1));
                mx = fmaxf(mx, __shfl_xor(mx, 2));
                mx = fmaxf(mx, __shfl_xor(mx, 4));
                mx = fmaxf(mx, __shfl_xor(mx, 8));
                float e = __expf(s - mx);
                float sm = e;
                sm += __shfl_xor(sm, 1); sm += __shfl_xor(sm, 2);
                sm += __shfl_xor(sm, 4); sm += __shfl_xor(sm, 8);
                float p = e / sm + bf2f(ewS[(q * 16 + c15) * 8 + h]);
                pS[(h * 16 + q) * 24 + c15] = f2bf(p);   // P = attn + ew
            }
            const int po = (h * 16 + c15) * 24 + (quad & 1) * 8;
            bf16x8 pa = *(const bf16x8*)&pS[po];
            bf16x8 vb = *(const bf16x8*)&vtS[po];
            if (quad >= 2) { pa = zf; vb = zf; }
            f32x4 xs = {0.f, 0.f, 0.f, 0.f};
            xs = MFMA(pa, vb, xs);
            const float vblk = vbS[h * 16 + c15];
            #pragma unroll
            for (int r = 0; r < 4; ++r) {
                const int tok = quad * 4 + r;
                float val = xs[r] + gS[tok * 8 + h] * vblk;
                unsigned short hi = f2bf(val);
                mhiS[tok * 136 + h * 16 + c15] = hi;
                mloS[tok * 136 + h * 16 + c15] = f2bf(val - bf2f(hi));
            }
        }
    }
    __syncthreads();

    // ---- phase 4: output projection (split-A MFMA) ----
    {
        bf16x8 mh[4], ml[4];
        #pragma unroll
        for (int kk = 0; kk < 4; ++kk) {
            int off = c15 * 136 + kk * 32 + quad * 8;
            mh[kk] = *(const bf16x8*)&mhiS[off];
            ml[kk] = *(const bf16x8*)&mloS[off];
        }
        float* op = out + (size_t)bid * 2048;
        #pragma unroll
        for (int it = 0; it < 2; ++it) {
            const int n0 = (wave * 2 + it) * 16;
            const unsigned short* wb = Wp + (n0 + c15) * 128 + quad * 8;
            f32x4 acc = {0.f, 0.f, 0.f, 0.f};
            #pragma unroll
            for (int kk = 0; kk < 4; ++kk) {
                bf16x8 bf = *(const bf16x8*)(wb + kk * 32);
                acc = MFMA(mh[kk], bf, acc);
                acc = MFMA(ml[kk], bf, acc);
            }
            const float bias = bproj[n0 + c15];
            #pragma unroll
            for (int r = 0; r < 4; ++r)
                op[(quad * 4 + r) * 128 + n0 + c15] = acc[r] + bias;
        }
    }
}

extern "C" void kernel_launch(void* const* d_in, const int* in_sizes, int n_in,
                              void* d_out, int out_size, void* d_ws, size_t ws_size,
                              hipStream_t stream) {
    const float* x     = (const float*)d_in[0];
    const int*   amask = (const int*)  d_in[1];
    const float* edge  = (const float*)d_in[2];
    const float* Wqkv  = (const float*)d_in[3];
    const float* bqkv  = (const float*)d_in[4];
    const float* Wproj = (const float*)d_in[5];
    const float* bproj = (const float*)d_in[6];
    const float* eg_w1 = (const float*)d_in[7];
    const float* eg_b1 = (const float*)d_in[8];
    const float* eg_w2 = (const float*)d_in[9];
    const float* eg_b2 = (const float*)d_in[10];
    const float* Wbr   = (const float*)d_in[11];
    const float* bbr   = (const float*)d_in[12];
    float* outp = (float*)d_out;

    unsigned short* Wbig = (unsigned short*)d_ws;                      // 400*128 bf16
    unsigned short* Wp   = (unsigned short*)((char*)d_ws + 400 * 128 * 2);

    hipLaunchKernelGGL(prep_kernel, dim3(264), dim3(256), 0, stream,
                       Wqkv, Wbr, Wproj, Wbig, Wp);
    hipLaunchKernelGGL(leaf_main, dim3(8192), dim3(256), 0, stream,
                       x, amask, edge, Wbig, Wp, bqkv, bproj,
                       eg_w1, eg_b1, eg_w2, eg_b2, bbr, outp);
}

// Round 4
// 150.214 us; speedup vs baseline: 6.7456x; 1.2297x over previous
//
#include <hip/hip_runtime.h>
#include <hip/hip_bf16.h>
#include <math.h>

// B=4, NB=2048 -> 8192 leaf blocks of L=16 tokens x C=128; H=8 heads x D=16.
typedef __attribute__((ext_vector_type(8))) short bf16x8;
typedef __attribute__((ext_vector_type(4))) float f32x4;
typedef __attribute__((ext_vector_type(4))) unsigned short us4;

struct bfpair { unsigned short hi, lo; };

static __device__ __forceinline__ unsigned short f2bf_rn(float f) {
    union { __hip_bfloat16 h; unsigned short u; } cv;
    cv.h = __float2bfloat16(f);
    return cv.u;
}
static __device__ __forceinline__ float bf2f(unsigned short u) {
    union { unsigned int i; float f; } cv;
    cv.i = ((unsigned int)u) << 16;
    return cv.f;
}
// truncation split: hi = trunc-bf16(f), lo = trunc-bf16(f - hi). 4 cheap ops.
static __device__ __forceinline__ bfpair split2(float f) {
    bfpair p;
    unsigned int u = __float_as_uint(f);
    p.hi = (unsigned short)(u >> 16);
    float r = f - __uint_as_float(u & 0xffff0000u);
    p.lo = (unsigned short)(__float_as_uint(r) >> 16);
    return p;
}
static __device__ __forceinline__ f32x4 MFMA(bf16x8 a, bf16x8 b, f32x4 c) {
    return __builtin_amdgcn_mfma_f32_16x16x32_bf16(a, b, c, 0, 0, 0);
}
static __device__ __forceinline__ float sigmoid_fast(float t) {
    return __builtin_amdgcn_rcpf(1.f + __expf(-t));
}

// ---- prep: Wbig = bf16([Wqkv(384); Wbr(8); zeros(8)]) [400][128]; Wp = bf16(Wproj)
__global__ __launch_bounds__(256) void prep_kernel(
    const float* __restrict__ Wqkv, const float* __restrict__ Wbr,
    const float* __restrict__ Wproj,
    unsigned short* __restrict__ Wbig, unsigned short* __restrict__ Wp)
{
    int i = blockIdx.x * 256 + threadIdx.x;
    if (i < 400 * 128) {
        int n = i >> 7, k = i & 127;
        float v = (n < 384) ? Wqkv[i] : (n < 392 ? Wbr[(n - 384) * 128 + k] : 0.f);
        Wbig[i] = f2bf_rn(v);
    } else {
        int j = i - 400 * 128;
        if (j < 128 * 128) Wp[j] = f2bf_rn(Wproj[j]);
    }
}

__global__ __launch_bounds__(256) void leaf_main(
    const float* __restrict__ x, const int* __restrict__ mask,
    const float* __restrict__ edge,
    const unsigned short* __restrict__ Wbig, const unsigned short* __restrict__ Wp,
    const float* __restrict__ bqkv, const float* __restrict__ bproj,
    const float* __restrict__ eg_w1, const float* __restrict__ eg_b1,
    const float* __restrict__ eg_w2, const float* __restrict__ eg_b2,
    const float* __restrict__ bbr, float* __restrict__ out)
{
    __shared__ unsigned short qhiS[16 * 136], qloS[16 * 136];   // q hi/lo (trunc split)
    __shared__ unsigned short khiS[16 * 136];                   // k rounded bf16
    __shared__ unsigned short vtS[128 * 24];                    // [h*16+d][tok(24 pad)]
    __shared__ unsigned short ewS[256 * 8];                     // [q*16+k][h]
    __shared__ float logitS[256];
    __shared__ float gS[16 * 8];                                // [tok][h]
    __shared__ float vbS[128];                                  // v_blk [h*16+d]
    __shared__ unsigned short pS[128 * 24];                     // [h*16+q][ktok(24)]
    __shared__ union XM {                                       // x (ph0/1) aliases x_mid (ph3/4)
        struct { unsigned short xhi[16 * 128], xlo[16 * 128]; } a;
        struct { unsigned short mhi[16 * 136], mlo[16 * 136]; } b;
    } xm;

    const int bid  = blockIdx.x;
    const int tid  = threadIdx.x;
    const int lane = tid & 63;
    const int wave = tid >> 6;
    const int c15  = lane & 15;
    const int quad = lane >> 4;
    const bf16x8 zf = {0, 0, 0, 0, 0, 0, 0, 0};

    // hoisted independent global loads (consumed in phase 2)
    const int    mv = mask[(size_t)bid * 256 + tid];
    const float4 ev = *(const float4*)&edge[((size_t)bid * 256 + tid) * 4];

    // ---- phase 0: stage x (f32 -> bf16 hi/lo trunc split, chunk-XOR swizzled) ----
    {
        const float4* xb = (const float4*)(x + (size_t)bid * 2048);
        #pragma unroll
        for (int ii = 0; ii < 2; ++ii) {
            int i = tid + ii * 256;
            float4 v = xb[i];
            int row = i >> 5, c4 = i & 31;
            int off = row * 128 + (((c4 >> 1) ^ (row & 7)) << 3) + ((c4 & 1) << 2);
            float f[4] = {v.x, v.y, v.z, v.w};
            us4 hi, lo;
            #pragma unroll
            for (int j = 0; j < 4; ++j) {
                bfpair p = split2(f[j]);
                hi[j] = p.hi;
                lo[j] = p.lo;
            }
            *(us4*)&xm.a.xhi[off] = hi;
            *(us4*)&xm.a.xlo[off] = lo;
        }
    }
    __syncthreads();

    // ---- phase 1: qkv + gate GEMM via MFMA (split-A hi+lo), v_blk by shuffle ----
    {
        bf16x8 ah[4], al[4];
        #pragma unroll
        for (int kk = 0; kk < 4; ++kk) {
            int off = c15 * 128 + (((kk * 4 + quad) ^ (c15 & 7)) << 3);
            ah[kk] = *(const bf16x8*)&xm.a.xhi[off];
            al[kk] = *(const bf16x8*)&xm.a.xlo[off];
        }
        const int ntiles = (wave == 0) ? 7 : 6;   // wave0 also owns gate tile 24
        int nt = wave;
        bf16x8 bcur[4];
        {
            const unsigned short* wb = Wbig + (nt * 16 + c15) * 128 + quad * 8;
            #pragma unroll
            for (int kk = 0; kk < 4; ++kk) bcur[kk] = *(const bf16x8*)(wb + kk * 32);
        }
        for (int it = 0; it < ntiles; ++it) {
            int ntn = (it == 5) ? 24 : wave + (it + 1) * 4;
            bf16x8 bnxt[4] = {zf, zf, zf, zf};
            if (it + 1 < ntiles) {
                const unsigned short* wb = Wbig + (ntn * 16 + c15) * 128 + quad * 8;
                #pragma unroll
                for (int kk = 0; kk < 4; ++kk) bnxt[kk] = *(const bf16x8*)(wb + kk * 32);
            }
            f32x4 acc = {0.f, 0.f, 0.f, 0.f};
            #pragma unroll
            for (int kk = 0; kk < 4; ++kk) {
                acc = MFMA(ah[kk], bcur[kk], acc);
                acc = MFMA(al[kk], bcur[kk], acc);
            }
            if (nt < 24) {
                float bias = bqkv[nt * 16 + c15];
                if (nt < 8) {
                    #pragma unroll
                    for (int r = 0; r < 4; ++r) {
                        int tok = quad * 4 + r, col = nt * 16 + c15;
                        bfpair p = split2(acc[r] + bias);
                        qhiS[tok * 136 + col] = p.hi;
                        qloS[tok * 136 + col] = p.lo;
                    }
                } else if (nt < 16) {
                    #pragma unroll
                    for (int r = 0; r < 4; ++r) {
                        int tok = quad * 4 + r, col = (nt - 8) * 16 + c15;
                        khiS[tok * 136 + col] = f2bf_rn(acc[r] + bias);
                    }
                } else {
                    int c = (nt - 16) * 16 + c15;   // h*16+d
                    #pragma unroll
                    for (int r = 0; r < 4; ++r)
                        vtS[c * 24 + quad * 4 + r] = f2bf_rn(acc[r] + bias);
                    float s = acc[0] + acc[1] + acc[2] + acc[3];
                    s += __shfl_xor(s, 16);
                    s += __shfl_xor(s, 32);
                    if (lane < 16) vbS[c] = s * 0.0625f + bias;   // mean over 16 tokens
                }
            } else if (c15 < 8) {
                float bias = bbr[c15];
                #pragma unroll
                for (int r = 0; r < 4; ++r)
                    gS[(quad * 4 + r) * 8 + c15] = sigmoid_fast(acc[r] + bias);
            }
            #pragma unroll
            for (int kk = 0; kk < 4; ++kk) bcur[kk] = bnxt[kk];
            nt = ntn;
        }
    }

    // ---- phase 2: edge-gate MLP (tanh-gelu) + mask/logits ----
    {
        const int q = tid >> 4, k = tid & 15;
        int s = mv;
        s += __shfl_xor(s, 1); s += __shfl_xor(s, 2);
        s += __shfl_xor(s, 4); s += __shfl_xor(s, 8);
        float m = (float)mv;
        if (q == k && s < 1) m = 1.f;
        float bp0, bp1, bp2, bp3;
        if (q == k) { bp0 = bp1 = bp2 = 0.f; bp3 = 1.f; }
        else        { bp0 = ev.x; bp1 = ev.y; bp2 = ev.z; bp3 = ev.w; }
        logitS[tid] = (m == 0.f) ? -INFINITY : bp3;
        float ew[8];
        #pragma unroll
        for (int h = 0; h < 8; ++h) ew[h] = eg_b2[h];
        #pragma unroll
        for (int j = 0; j < 16; ++j) {
            float z = eg_w1[j * 4 + 0] * bp0 + eg_w1[j * 4 + 1] * bp1 +
                      eg_w1[j * 4 + 2] * bp2 + eg_w1[j * 4 + 3] * bp3 + eg_b1[j];
            // gelu(z) ~= z * sigmoid(z*(1.5957691 + 0.0713548*z^2))
            float g = z * sigmoid_fast(z * (1.5957691216f + 0.071354816f * z * z));
            #pragma unroll
            for (int h = 0; h < 8; ++h) ew[h] += eg_w2[h * 16 + j] * g;
        }
        #pragma unroll
        for (int h = 0; h < 8; ++h)
            ewS[tid * 8 + h] = (m == 0.f) ? (unsigned short)0
                             : (unsigned short)(__float_as_uint(ew[h]) >> 16);
    }
    __syncthreads();

    // ---- phase 3: attention (2 heads per wave) ----
    {
        #pragma unroll
        for (int hh = 0; hh < 2; ++hh) {
            const int h = 2 * wave + hh;
            const int fo = c15 * 136 + h * 16 + (quad & 1) * 8;
            bf16x8 qh_ = *(const bf16x8*)&qhiS[fo];
            bf16x8 ql_ = *(const bf16x8*)&qloS[fo];
            bf16x8 kh_ = *(const bf16x8*)&khiS[fo];
            if (quad >= 2) { qh_ = zf; ql_ = zf; kh_ = zf; }
            f32x4 sc = {0.f, 0.f, 0.f, 0.f};
            sc = MFMA(qh_, kh_, sc);
            sc = MFMA(ql_, kh_, sc);
            #pragma unroll
            for (int r = 0; r < 4; ++r) {
                const int q = quad * 4 + r;
                float s = sc[r] * 0.25f + logitS[q * 16 + c15];
                float mx = s;
                mx = fmaxf(mx, __shfl_xor(mx, 1));
                mx = fmaxf(mx, __shfl_xor(mx, 2));
                mx = fmaxf(mx, __shfl_xor(mx, 4));
                mx = fmaxf(mx, __shfl_xor(mx, 8));
                float e = __expf(s - mx);
                float sm = e;
                sm += __shfl_xor(sm, 1); sm += __shfl_xor(sm, 2);
                sm += __shfl_xor(sm, 4); sm += __shfl_xor(sm, 8);
                float p = e * __builtin_amdgcn_rcpf(sm) + bf2f(ewS[(q * 16 + c15) * 8 + h]);
                pS[(h * 16 + q) * 24 + c15] = f2bf_rn(p);
            }
            const int po = (h * 16 + c15) * 24 + (quad & 1) * 8;
            bf16x8 pa = *(const bf16x8*)&pS[po];
            bf16x8 vb = *(const bf16x8*)&vtS[po];
            if (quad >= 2) { pa = zf; vb = zf; }
            f32x4 xs = {0.f, 0.f, 0.f, 0.f};
            xs = MFMA(pa, vb, xs);
            const float vblk = vbS[h * 16 + c15];
            #pragma unroll
            for (int r = 0; r < 4; ++r) {
                const int tok = quad * 4 + r;
                float val = xs[r] + gS[tok * 8 + h] * vblk;
                bfpair p = split2(val);
                xm.b.mhi[tok * 136 + h * 16 + c15] = p.hi;
                xm.b.mlo[tok * 136 + h * 16 + c15] = p.lo;
            }
        }
    }
    __syncthreads();

    // ---- phase 4: output projection (split-A MFMA) ----
    {
        bf16x8 mh[4], ml[4];
        #pragma unroll
        for (int kk = 0; kk < 4; ++kk) {
            int off = c15 * 136 + kk * 32 + quad * 8;
            mh[kk] = *(const bf16x8*)&xm.b.mhi[off];
            ml[kk] = *(const bf16x8*)&xm.b.mlo[off];
        }
        float* op = out + (size_t)bid * 2048;
        #pragma unroll
        for (int it = 0; it < 2; ++it) {
            const int n0 = (wave * 2 + it) * 16;
            const unsigned short* wb = Wp + (n0 + c15) * 128 + quad * 8;
            f32x4 acc = {0.f, 0.f, 0.f, 0.f};
            #pragma unroll
            for (int kk = 0; kk < 4; ++kk) {
                bf16x8 bf = *(const bf16x8*)(wb + kk * 32);
                acc = MFMA(mh[kk], bf, acc);
                acc = MFMA(ml[kk], bf, acc);
            }
            const float bias = bproj[n0 + c15];
            #pragma unroll
            for (int r = 0; r < 4; ++r)
                op[(quad * 4 + r) * 128 + n0 + c15] = acc[r] + bias;
        }
    }
}

extern "C" void kernel_launch(void* const* d_in, const int* in_sizes, int n_in,
                              void* d_out, int out_size, void* d_ws, size_t ws_size,
                              hipStream_t stream) {
    const float* x     = (const float*)d_in[0];
    const int*   amask = (const int*)  d_in[1];
    const float* edge  = (const float*)d_in[2];
    const float* Wqkv  = (const float*)d_in[3];
    const float* bqkv  = (const float*)d_in[4];
    const float* Wproj = (const float*)d_in[5];
    const float* bproj = (const float*)d_in[6];
    const float* eg_w1 = (const float*)d_in[7];
    const float* eg_b1 = (const float*)d_in[8];
    const float* eg_w2 = (const float*)d_in[9];
    const float* eg_b2 = (const float*)d_in[10];
    const float* Wbr   = (const float*)d_in[11];
    const float* bbr   = (const float*)d_in[12];
    float* outp = (float*)d_out;

    unsigned short* Wbig = (unsigned short*)d_ws;                      // 400*128 bf16
    unsigned short* Wp   = (unsigned short*)((char*)d_ws + 400 * 128 * 2);

    hipLaunchKernelGGL(prep_kernel, dim3(264), dim3(256), 0, stream,
                       Wqkv, Wbr, Wproj, Wbig, Wp);
    hipLaunchKernelGGL(leaf_main, dim3(8192), dim3(256), 0, stream,
                       x, amask, edge, Wbig, Wp, bqkv, bproj,
                       eg_w1, eg_b1, eg_w2, eg_b2, bbr, outp);
}